// Round 1
// baseline (194.764 us; speedup 1.0000x reference)
//
#include <hip/hip_runtime.h>

#define BATCH 8
#define SEQ   1024
#define DIM   128
#define HEADS 8
#define NQKV  3072
#define QSZ   (BATCH*HEADS*SEQ*DIM)   // 8388608 bf16 elements per tensor

typedef __attribute__((ext_vector_type(4))) float floatx4;
typedef __attribute__((ext_vector_type(8))) __bf16 bf16x8;

__device__ __forceinline__ unsigned short bf16bits(float f) {
  union { float f; unsigned int u; } v;
  v.f = f;
  unsigned int u = v.u;
  u += 0x7fffu + ((u >> 16) & 1u);   // RNE
  return (unsigned short)(u >> 16);
}

// ---------------------------------------------------------------------------
// Kernel 1: qkv = x @ w_qkv, write Q (scaled), K as [bh][n][d], V^T as [bh][d][n]
// tile: 128 M x 64 N, full K=128 staged in LDS as bf16
// ---------------------------------------------------------------------------
__global__ __launch_bounds__(256, 2)
void qkv_kernel(const float* __restrict__ x, const float* __restrict__ w,
                unsigned short* __restrict__ ws) {
  const int tn = blockIdx.x % 48;
  const int tm = blockIdx.x / 48;
  const int m0 = tm * 128, n0 = tn * 64;

  __shared__ __align__(16) unsigned short As[128 * 136];  // [m][k]
  __shared__ __align__(16) unsigned short Bt[64 * 136];   // [n][k]

  const int t = threadIdx.x;
  const int lane = t & 63, wv = t >> 6;
  const int l16 = lane & 15, qd = lane >> 4;

  // stage A: x[m0..+128][0..128] fp32 -> bf16, coalesced float4 loads
  for (int i = 0; i < 16; ++i) {
    int linear = i * 1024 + t * 4;
    int r = linear >> 7, c = linear & 127;
    float4 f = *(const float4*)(x + (size_t)(m0 + r) * DIM + c);
    ushort4 pk;
    pk.x = bf16bits(f.x); pk.y = bf16bits(f.y);
    pk.z = bf16bits(f.z); pk.w = bf16bits(f.w);
    *(ushort4*)&As[r * 136 + c] = pk;
  }
  // stage B transposed: w[k][n0+n] -> Bt[n][k]; loads coalesced over n
  {
    const int n  = t & 63;
    const int kb = (t >> 6) * 4;
    for (int i = 0; i < 8; ++i) {
      int kk = kb + i * 16;
      ushort4 pk;
      pk.x = bf16bits(w[(size_t)(kk + 0) * NQKV + n0 + n]);
      pk.y = bf16bits(w[(size_t)(kk + 1) * NQKV + n0 + n]);
      pk.z = bf16bits(w[(size_t)(kk + 2) * NQKV + n0 + n]);
      pk.w = bf16bits(w[(size_t)(kk + 3) * NQKV + n0 + n]);
      *(ushort4*)&Bt[n * 136 + kk] = pk;
    }
  }
  __syncthreads();

  const int mo = (wv >> 1) * 64, no = (wv & 1) * 32;
  floatx4 acc[4][2] = {};
  for (int k0 = 0; k0 < 128; k0 += 32) {
    bf16x8 af[4], bfv[2];
    for (int mt = 0; mt < 4; ++mt)
      af[mt] = *(const bf16x8*)&As[(mo + mt * 16 + l16) * 136 + k0 + qd * 8];
    for (int nt = 0; nt < 2; ++nt)
      bfv[nt] = *(const bf16x8*)&Bt[(no + nt * 16 + l16) * 136 + k0 + qd * 8];
    for (int mt = 0; mt < 4; ++mt)
      for (int nt = 0; nt < 2; ++nt)
        acc[mt][nt] = __builtin_amdgcn_mfma_f32_16x16x32_bf16(af[mt], bfv[nt], acc[mt][nt], 0, 0, 0);
  }

  const int s = n0 >> 10;                 // 0=q 1=k 2=v
  const int h = (n0 & 1023) >> 7;         // head
  const float scale = (s == 0) ? 0.08838834764831845f : 1.0f;  // 128^-0.5 folded into Q
  for (int mt = 0; mt < 4; ++mt)
    for (int nt = 0; nt < 2; ++nt)
      for (int r = 0; r < 4; ++r) {
        int mrow = m0 + mo + mt * 16 + qd * 4 + r;
        int d    = (n0 & 127) + no + nt * 16 + l16;
        int b = mrow >> 10, n = mrow & 1023;
        int bh = b * HEADS + h;
        size_t off;
        if (s == 2) off = (size_t)2 * QSZ + ((size_t)bh * DIM + d) * SEQ + n;   // V^T
        else        off = (size_t)s * QSZ + ((size_t)bh * SEQ + n) * DIM + d;   // Q / K
        ws[off] = bf16bits(acc[mt][nt][r] * scale);
      }
}

// ---------------------------------------------------------------------------
// Kernel 2: flash attention. block = (bh, qtile of 128); wave = 32 q rows.
// 64-key tiles; online softmax; P via wave-private LDS roundtrip.
// ---------------------------------------------------------------------------
__global__ __launch_bounds__(256, 2)
void attn_kernel(unsigned short* __restrict__ ws) {
  const unsigned short* Q  = ws;
  const unsigned short* K  = ws + (size_t)QSZ;
  const unsigned short* VT = ws + (size_t)2 * QSZ;
  unsigned short*       Z  = ws + (size_t)3 * QSZ;

  const int bh = blockIdx.x >> 3;
  const int qt = blockIdx.x & 7;
  const int t = threadIdx.x, lane = t & 63, wv = t >> 6;
  const int l16 = lane & 15, qd = lane >> 4;

  __shared__ __align__(16) unsigned short Ks[64 * 136];   // [key][d]
  __shared__ __align__(16) unsigned short Vs[128 * 72];   // [d][key]
  __shared__ __align__(16) unsigned short Pw[4][32 * 72]; // per-wave [qrow][key]

  // Q fragments for this wave's 32 rows, kept in registers for all key tiles
  const size_t qbase = ((size_t)bh * SEQ + qt * 128 + wv * 32) * DIM;
  bf16x8 qf[2][4];
  for (int mt = 0; mt < 2; ++mt)
    for (int ks = 0; ks < 4; ++ks)
      qf[mt][ks] = *(const bf16x8*)(Q + qbase + (size_t)(mt * 16 + l16) * DIM + ks * 32 + qd * 8);

  floatx4 o[2][8] = {};
  float mrow[2][4], lrow[2][4];
  for (int mt = 0; mt < 2; ++mt)
    for (int r = 0; r < 4; ++r) { mrow[mt][r] = -1e30f; lrow[mt][r] = 0.f; }

  for (int kt = 0; kt < 16; ++kt) {
    const int kb = kt * 64;
    __syncthreads();
    // stage K tile [64][128]
    for (int i = 0; i < 4; ++i) {
      int linear = i * 2048 + t * 8;
      int key = linear >> 7, d0 = linear & 127;
      *(bf16x8*)&Ks[key * 136 + d0] =
          *(const bf16x8*)(K + ((size_t)bh * SEQ + kb + key) * DIM + d0);
    }
    // stage V^T tile [128][64]
    for (int i = 0; i < 4; ++i) {
      int linear = i * 2048 + t * 8;
      int d = linear >> 6, kk = linear & 63;
      *(bf16x8*)&Vs[d * 72 + kk] =
          *(const bf16x8*)(VT + ((size_t)bh * DIM + d) * SEQ + kb + kk);
    }
    __syncthreads();

    // S = Q(32x128) @ K^T(128x64)
    floatx4 s[2][4] = {};
    for (int ks = 0; ks < 4; ++ks) {
      bf16x8 kf[4];
      for (int nt = 0; nt < 4; ++nt)
        kf[nt] = *(const bf16x8*)&Ks[(nt * 16 + l16) * 136 + ks * 32 + qd * 8];
      for (int mt = 0; mt < 2; ++mt)
        for (int nt = 0; nt < 4; ++nt)
          s[mt][nt] = __builtin_amdgcn_mfma_f32_16x16x32_bf16(qf[mt][ks], kf[nt], s[mt][nt], 0, 0, 0);
    }

    // online softmax (scale already folded into Q)
    for (int mt = 0; mt < 2; ++mt)
      for (int r = 0; r < 4; ++r) {
        float mx = fmaxf(fmaxf(s[mt][0][r], s[mt][1][r]), fmaxf(s[mt][2][r], s[mt][3][r]));
        for (int off = 1; off < 16; off <<= 1)
          mx = fmaxf(mx, __shfl_xor(mx, off, 64));
        float mnew = fmaxf(mrow[mt][r], mx);
        float alpha = __expf(mrow[mt][r] - mnew);
        mrow[mt][r] = mnew;
        float rsum = 0.f;
        for (int nt = 0; nt < 4; ++nt) {
          float p = __expf(s[mt][nt][r] - mnew);
          s[mt][nt][r] = p;
          rsum += p;
        }
        for (int off = 1; off < 16; off <<= 1)
          rsum += __shfl_xor(rsum, off, 64);
        lrow[mt][r] = lrow[mt][r] * alpha + rsum;
        for (int nt = 0; nt < 8; ++nt) o[mt][nt][r] *= alpha;
      }

    // P (C/D layout) -> bf16 -> wave-private LDS -> A-operand layout
    unsigned short* pw = Pw[wv];
    for (int mt = 0; mt < 2; ++mt)
      for (int nt = 0; nt < 4; ++nt)
        for (int r = 0; r < 4; ++r)
          pw[(mt * 16 + qd * 4 + r) * 72 + nt * 16 + l16] = bf16bits(s[mt][nt][r]);

    // O += P(32x64) @ V(64x128)
    for (int ks = 0; ks < 2; ++ks) {
      bf16x8 pf[2];
      for (int mt = 0; mt < 2; ++mt)
        pf[mt] = *(const bf16x8*)&pw[(mt * 16 + l16) * 72 + ks * 32 + qd * 8];
      for (int nt = 0; nt < 8; ++nt) {
        bf16x8 vf = *(const bf16x8*)&Vs[(nt * 16 + l16) * 72 + ks * 32 + qd * 8];
        for (int mt = 0; mt < 2; ++mt)
          o[mt][nt] = __builtin_amdgcn_mfma_f32_16x16x32_bf16(pf[mt], vf, o[mt][nt], 0, 0, 0);
      }
    }
  }

  // epilogue: z = o/l -> Z[b][n][h*128+d]
  const int b = bh >> 3, h = bh & 7;
  for (int mt = 0; mt < 2; ++mt)
    for (int r = 0; r < 4; ++r) {
      float inv = 1.f / lrow[mt][r];
      int n = qt * 128 + wv * 32 + mt * 16 + qd * 4 + r;
      size_t rowoff = ((size_t)b * SEQ + n) * (HEADS * DIM) + h * DIM;
      for (int nt = 0; nt < 8; ++nt)
        Z[rowoff + nt * 16 + l16] = bf16bits(o[mt][nt][r] * inv);
    }
}

// ---------------------------------------------------------------------------
// Kernel 3: out = Z(8192x1024) @ w_out(1024x128) + b_out, fp32 out
// tile 64 M x 128 N, K staged in 128-chunks
// ---------------------------------------------------------------------------
__global__ __launch_bounds__(256, 2)
void out_kernel(const unsigned short* __restrict__ Z, const float* __restrict__ w,
                const float* __restrict__ bias, float* __restrict__ out) {
  const int m0 = blockIdx.x * 64;
  __shared__ __align__(16) unsigned short As[64 * 136];   // [m][k]
  __shared__ __align__(16) unsigned short Bt[128 * 136];  // [n][k]

  const int t = threadIdx.x, lane = t & 63, wv = t >> 6;
  const int l16 = lane & 15, qd = lane >> 4;

  floatx4 acc[8] = {};
  for (int k0 = 0; k0 < 1024; k0 += 128) {
    __syncthreads();
    // stage A from Z (bf16 already)
    for (int i = 0; i < 4; ++i) {
      int linear = i * 2048 + t * 8;
      int r = linear >> 7, c = linear & 127;
      *(bf16x8*)&As[r * 136 + c] =
          *(const bf16x8*)(Z + (size_t)(m0 + r) * 1024 + k0 + c);
    }
    // stage B transposed: w[k0+kk][n] -> Bt[n][kk]
    {
      const int n  = t & 127;
      const int kb = (t >> 7) * 4;
      for (int i = 0; i < 16; ++i) {
        int kk = kb + i * 8;
        ushort4 pk;
        pk.x = bf16bits(w[(size_t)(k0 + kk + 0) * DIM + n]);
        pk.y = bf16bits(w[(size_t)(k0 + kk + 1) * DIM + n]);
        pk.z = bf16bits(w[(size_t)(k0 + kk + 2) * DIM + n]);
        pk.w = bf16bits(w[(size_t)(k0 + kk + 3) * DIM + n]);
        *(ushort4*)&Bt[n * 136 + kk] = pk;
      }
    }
    __syncthreads();

    for (int ks = 0; ks < 4; ++ks) {
      bf16x8 af = *(const bf16x8*)&As[(wv * 16 + l16) * 136 + ks * 32 + qd * 8];
      for (int nt = 0; nt < 8; ++nt) {
        bf16x8 bfv = *(const bf16x8*)&Bt[(nt * 16 + l16) * 136 + ks * 32 + qd * 8];
        acc[nt] = __builtin_amdgcn_mfma_f32_16x16x32_bf16(af, bfv, acc[nt], 0, 0, 0);
      }
    }
  }

  for (int nt = 0; nt < 8; ++nt)
    for (int r = 0; r < 4; ++r) {
      int row = m0 + wv * 16 + qd * 4 + r;
      int col = nt * 16 + l16;
      out[(size_t)row * DIM + col] = acc[nt][r] + bias[col];
    }
}

extern "C" void kernel_launch(void* const* d_in, const int* in_sizes, int n_in,
                              void* d_out, int out_size, void* d_ws, size_t ws_size,
                              hipStream_t stream) {
  (void)in_sizes; (void)n_in; (void)out_size; (void)ws_size;
  const float* x     = (const float*)d_in[0];
  const float* w_qkv = (const float*)d_in[1];
  const float* w_out = (const float*)d_in[2];
  const float* b_out = (const float*)d_in[3];
  float* out = (float*)d_out;
  unsigned short* ws = (unsigned short*)d_ws;   // needs 4*QSZ*2 = 64 MiB

  qkv_kernel<<<dim3(64 * 48), dim3(256), 0, stream>>>(x, w_qkv, ws);
  attn_kernel<<<dim3(64 * 8), dim3(256), 0, stream>>>(ws);
  out_kernel<<<dim3(128), dim3(256), 0, stream>>>(ws + (size_t)3 * QSZ, w_out, b_out, out);
}

// Round 2
// 180.292 us; speedup vs baseline: 1.0803x; 1.0803x over previous
//
#include <hip/hip_runtime.h>

#define BATCH 8
#define SEQ   1024
#define DIM   128
#define HEADS 8
#define NQKV  3072
#define QSZ   (BATCH*HEADS*SEQ*DIM)   // 8388608 bf16 elements per tensor

typedef __attribute__((ext_vector_type(4))) float floatx4;
typedef __attribute__((ext_vector_type(8))) __bf16 bf16x8;

__device__ __forceinline__ unsigned short bf16bits(float f) {
  union { float f; unsigned int u; } v;
  v.f = f;
  unsigned int u = v.u;
  u += 0x7fffu + ((u >> 16) & 1u);   // RNE
  return (unsigned short)(u >> 16);
}

// ws layout (ushort offsets):
//   Q  : 0          (dead after attn; prep2 puts w_out^T bf16 at offset 0)
//   K  : QSZ
//   VT : 2*QSZ
//   Z  : 3*QSZ      (prep1 stashes xb at 3*QSZ, wqt at 3*QSZ+XBSZ; attn's Z
//                    writes clobber them after qkv is done reading)
#define XBSZ  (BATCH*SEQ*DIM)         // 1048576
#define WQTSZ (NQKV*DIM)              // 393216

// ---------------------------------------------------------------------------
// prep1: xb = bf16(x) [8192][128]; wqt = bf16(w_qkv^T) [3072][128]
// ---------------------------------------------------------------------------
__global__ __launch_bounds__(256, 2)
void prep1_kernel(const float* __restrict__ x, const float* __restrict__ wqkv,
                  unsigned short* __restrict__ ws) {
  unsigned short* xb  = ws + (size_t)3 * QSZ;
  unsigned short* wqt = xb + XBSZ;
  const int blk = blockIdx.x, t = threadIdx.x;
  if (blk < 512) {
    size_t base = (size_t)blk * 2048 + t * 8;
    float4 f0 = *(const float4*)(x + base);
    float4 f1 = *(const float4*)(x + base + 4);
    ushort4 a, b;
    a.x = bf16bits(f0.x); a.y = bf16bits(f0.y); a.z = bf16bits(f0.z); a.w = bf16bits(f0.w);
    b.x = bf16bits(f1.x); b.y = bf16bits(f1.y); b.z = bf16bits(f1.z); b.w = bf16bits(f1.w);
    *(ushort4*)(xb + base)     = a;
    *(ushort4*)(xb + base + 4) = b;
  } else {
    __shared__ __align__(16) unsigned short L[64 * 136];
    const int n0 = (blk - 512) * 64;
    const int n = t & 63, kg = t >> 6;
    for (int i = 0; i < 32; ++i) {
      int k = kg * 32 + i;
      L[n * 136 + k] = bf16bits(wqkv[(size_t)k * NQKV + n0 + n]);
    }
    __syncthreads();
    for (int i = 0; i < 4; ++i) {
      int cid = i * 256 + t;
      int r = cid >> 4, ch = cid & 15;
      *(bf16x8*)(wqt + (size_t)(n0 + r) * 128 + ch * 8) = *(const bf16x8*)&L[r * 136 + ch * 8];
    }
  }
}

// ---------------------------------------------------------------------------
// prep2 (after attn): wot = bf16(w_out^T) [128][1024] at ws offset 0
// ---------------------------------------------------------------------------
__global__ __launch_bounds__(256, 2)
void prep2_kernel(const float* __restrict__ wout, unsigned short* __restrict__ ws) {
  __shared__ __align__(16) unsigned short L[128 * 136];
  const int k0 = blockIdx.x * 128, t = threadIdx.x;
  const int n = t & 127, kg = t >> 7;
  for (int i = 0; i < 64; ++i) {
    int k = kg * 64 + i;
    L[n * 136 + k] = bf16bits(wout[(size_t)(k0 + k) * DIM + n]);
  }
  __syncthreads();
  for (int i = 0; i < 8; ++i) {
    int cid = i * 256 + t;
    int r = cid >> 4, ch = cid & 15;
    *(bf16x8*)(ws + (size_t)r * 1024 + k0 + ch * 8) = *(const bf16x8*)&L[r * 136 + ch * 8];
  }
}

// ---------------------------------------------------------------------------
// Kernel 1: qkv = xb @ wqt^T; write Q (scaled), K [bh][n][d], V^T [bh][d][n]
// tile 128M x 64N, K=128; epilogue repacked through LDS for 16B stores
// ---------------------------------------------------------------------------
__global__ __launch_bounds__(256, 2)
void qkv_kernel(unsigned short* __restrict__ ws) {
  const unsigned short* xb  = ws + (size_t)3 * QSZ;
  const unsigned short* wqt = xb + XBSZ;

  const int tn = blockIdx.x % 48;
  const int tm = blockIdx.x / 48;
  const int m0 = tm * 128, n0 = tn * 64;

  __shared__ __align__(16) unsigned short As[128 * 136];  // [m][k]; reused as repack buf
  __shared__ __align__(16) unsigned short Bt[64 * 136];   // [n][k]

  const int t = threadIdx.x;
  const int lane = t & 63, wv = t >> 6;
  const int l16 = lane & 15, qd = lane >> 4;

  for (int i = 0; i < 8; ++i) {        // A: 128x128 bf16, 16B chunks
    int cid = i * 256 + t;
    int r = cid >> 4, ch = cid & 15;
    *(bf16x8*)&As[r * 136 + ch * 8] = *(const bf16x8*)(xb + (size_t)(m0 + r) * 128 + ch * 8);
  }
  for (int i = 0; i < 4; ++i) {        // B: 64x128 bf16
    int cid = i * 256 + t;
    int r = cid >> 4, ch = cid & 15;
    *(bf16x8*)&Bt[r * 136 + ch * 8] = *(const bf16x8*)(wqt + (size_t)(n0 + r) * 128 + ch * 8);
  }
  __syncthreads();

  const int mo = (wv >> 1) * 64, no = (wv & 1) * 32;
  floatx4 acc[4][2] = {};
  for (int k0 = 0; k0 < 128; k0 += 32) {
    bf16x8 af[4], bfv[2];
    for (int mt = 0; mt < 4; ++mt)
      af[mt] = *(const bf16x8*)&As[(mo + mt * 16 + l16) * 136 + k0 + qd * 8];
    for (int nt = 0; nt < 2; ++nt)
      bfv[nt] = *(const bf16x8*)&Bt[(no + nt * 16 + l16) * 136 + k0 + qd * 8];
    for (int mt = 0; mt < 4; ++mt)
      for (int nt = 0; nt < 2; ++nt)
        acc[mt][nt] = __builtin_amdgcn_mfma_f32_16x16x32_bf16(af[mt], bfv[nt], acc[mt][nt], 0, 0, 0);
  }

  const int s = n0 >> 10;                 // 0=q 1=k 2=v
  const int h = (n0 & 1023) >> 7;         // head
  const int d0 = n0 & 127;                // 0 or 64 within the head
  const float scale = (s == 0) ? 0.08838834764831845f : 1.0f;  // 128^-0.5 folded into Q

  __syncthreads();                        // done reading As/Bt; reuse As as Cs
  unsigned short* Cs = As;
  if (s < 2) {                            // Cs[m][c], stride 72
    for (int mt = 0; mt < 4; ++mt)
      for (int nt = 0; nt < 2; ++nt)
        for (int r = 0; r < 4; ++r)
          Cs[(mo + mt * 16 + qd * 4 + r) * 72 + no + nt * 16 + l16] =
              bf16bits(acc[mt][nt][r] * scale);
  } else {                                // Cs[c][m], stride 136 (V^T)
    for (int mt = 0; mt < 4; ++mt)
      for (int nt = 0; nt < 2; ++nt)
        for (int r = 0; r < 4; ++r)
          Cs[(no + nt * 16 + l16) * 136 + mo + mt * 16 + qd * 4 + r] =
              bf16bits(acc[mt][nt][r]);
  }
  __syncthreads();

  const int b = m0 >> 10, nseq0 = m0 & 1023;
  const int bh = b * HEADS + h;
  if (s < 2) {
    // 128 rows x 8 chunks-of-8: dst = s*QSZ + (bh*1024 + nseq)*128 + d0 + ch*8
    unsigned short* dst = ws + (size_t)s * QSZ + ((size_t)bh * SEQ + nseq0) * 128 + d0;
    for (int i = 0; i < 4; ++i) {
      int cid = i * 256 + t;
      int mr = cid >> 3, ch = cid & 7;
      *(bf16x8*)(dst + (size_t)mr * 128 + ch * 8) = *(const bf16x8*)&Cs[mr * 72 + ch * 8];
    }
  } else {
    // 64 d-rows x 16 chunks-of-8: dst = 2*QSZ + (bh*128 + d0+c)*1024 + nseq0 + ch*8
    unsigned short* dst = ws + (size_t)2 * QSZ + ((size_t)bh * DIM + d0) * SEQ + nseq0;
    for (int i = 0; i < 4; ++i) {
      int cid = i * 256 + t;
      int cr = cid >> 4, ch = cid & 15;
      *(bf16x8*)(dst + (size_t)cr * SEQ + ch * 8) = *(const bf16x8*)&Cs[cr * 136 + ch * 8];
    }
  }
}

// ---------------------------------------------------------------------------
// Kernel 2: flash attention. bh = blk&63 (XCD swizzle: all 8 q-tiles of a bh
// on one XCD -> K/V served from L2). Register prefetch of next K/V tile.
// ---------------------------------------------------------------------------
__global__ __launch_bounds__(256, 2)
void attn_kernel(unsigned short* __restrict__ ws) {
  const unsigned short* Q  = ws;
  const unsigned short* K  = ws + (size_t)QSZ;
  const unsigned short* VT = ws + (size_t)2 * QSZ;
  unsigned short*       Z  = ws + (size_t)3 * QSZ;

  const int bh = blockIdx.x & 63;
  const int qt = blockIdx.x >> 6;
  const int t = threadIdx.x, lane = t & 63, wv = t >> 6;
  const int l16 = lane & 15, qd = lane >> 4;

  __shared__ __align__(16) unsigned short Ks[64 * 136];   // [key][d]
  __shared__ __align__(16) unsigned short Vs[128 * 72];   // [d][key]
  __shared__ __align__(16) unsigned short Pw[4][32 * 72]; // per-wave [qrow][key]

  // Q fragments for this wave's 32 rows, kept in registers for all key tiles
  const size_t qbase = ((size_t)bh * SEQ + qt * 128 + wv * 32) * DIM;
  bf16x8 qf[2][4];
  for (int mt = 0; mt < 2; ++mt)
    for (int ks = 0; ks < 4; ++ks)
      qf[mt][ks] = *(const bf16x8*)(Q + qbase + (size_t)(mt * 16 + l16) * DIM + ks * 32 + qd * 8);

  // per-thread staging indices
  int kkey[4], kd0[4], vd[4], vkk[4];
  for (int i = 0; i < 4; ++i) {
    int linear = i * 2048 + t * 8;
    kkey[i] = linear >> 7; kd0[i] = linear & 127;
    vd[i]   = linear >> 6; vkk[i] = linear & 63;
  }
  const unsigned short* Kb = K  + (size_t)bh * SEQ * DIM;
  const unsigned short* Vb = VT + (size_t)bh * DIM * SEQ;

  bf16x8 kreg[4], vreg[4];
  auto fetch = [&](int kb) {
    for (int i = 0; i < 4; ++i) {
      kreg[i] = *(const bf16x8*)(Kb + (size_t)(kb + kkey[i]) * DIM + kd0[i]);
      vreg[i] = *(const bf16x8*)(Vb + (size_t)vd[i] * SEQ + kb + vkk[i]);
    }
  };
  fetch(0);

  floatx4 o[2][8] = {};
  float mrow[2][4], lrow[2][4];
  for (int mt = 0; mt < 2; ++mt)
    for (int r = 0; r < 4; ++r) { mrow[mt][r] = -1e30f; lrow[mt][r] = 0.f; }

  for (int kt = 0; kt < 16; ++kt) {
    __syncthreads();                       // previous iter's LDS reads done
    for (int i = 0; i < 4; ++i) {
      *(bf16x8*)&Ks[kkey[i] * 136 + kd0[i]] = kreg[i];
      *(bf16x8*)&Vs[vd[i] * 72 + vkk[i]]    = vreg[i];
    }
    __syncthreads();
    if (kt < 15) fetch((kt + 1) * 64);     // prefetch overlaps compute below

    // S = Q(32x128) @ K^T(128x64)
    floatx4 s[2][4] = {};
    for (int ks = 0; ks < 4; ++ks) {
      bf16x8 kf[4];
      for (int nt = 0; nt < 4; ++nt)
        kf[nt] = *(const bf16x8*)&Ks[(nt * 16 + l16) * 136 + ks * 32 + qd * 8];
      for (int mt = 0; mt < 2; ++mt)
        for (int nt = 0; nt < 4; ++nt)
          s[mt][nt] = __builtin_amdgcn_mfma_f32_16x16x32_bf16(qf[mt][ks], kf[nt], s[mt][nt], 0, 0, 0);
    }

    // online softmax (scale folded into Q)
    for (int mt = 0; mt < 2; ++mt)
      for (int r = 0; r < 4; ++r) {
        float mx = fmaxf(fmaxf(s[mt][0][r], s[mt][1][r]), fmaxf(s[mt][2][r], s[mt][3][r]));
        for (int off = 1; off < 16; off <<= 1)
          mx = fmaxf(mx, __shfl_xor(mx, off, 64));
        float mnew = fmaxf(mrow[mt][r], mx);
        float alpha = __expf(mrow[mt][r] - mnew);
        mrow[mt][r] = mnew;
        float rsum = 0.f;
        for (int nt = 0; nt < 4; ++nt) {
          float p = __expf(s[mt][nt][r] - mnew);
          s[mt][nt][r] = p;
          rsum += p;
        }
        for (int off = 1; off < 16; off <<= 1)
          rsum += __shfl_xor(rsum, off, 64);
        lrow[mt][r] = lrow[mt][r] * alpha + rsum;
        for (int nt = 0; nt < 8; ++nt) o[mt][nt][r] *= alpha;
      }

    // P (C/D layout) -> bf16 -> wave-private LDS -> A-operand layout
    unsigned short* pw = Pw[wv];
    for (int mt = 0; mt < 2; ++mt)
      for (int nt = 0; nt < 4; ++nt)
        for (int r = 0; r < 4; ++r)
          pw[(mt * 16 + qd * 4 + r) * 72 + nt * 16 + l16] = bf16bits(s[mt][nt][r]);

    // O += P(32x64) @ V(64x128)
    for (int ks = 0; ks < 2; ++ks) {
      bf16x8 pf[2];
      for (int mt = 0; mt < 2; ++mt)
        pf[mt] = *(const bf16x8*)&pw[(mt * 16 + l16) * 72 + ks * 32 + qd * 8];
      for (int nt = 0; nt < 8; ++nt) {
        bf16x8 vf = *(const bf16x8*)&Vs[(nt * 16 + l16) * 72 + ks * 32 + qd * 8];
        for (int mt = 0; mt < 2; ++mt)
          o[mt][nt] = __builtin_amdgcn_mfma_f32_16x16x32_bf16(pf[mt], vf, o[mt][nt], 0, 0, 0);
      }
    }
  }

  // epilogue: z = o/l -> Z[b][n][h*128+d]
  const int b = bh >> 3, h = bh & 7;
  for (int mt = 0; mt < 2; ++mt)
    for (int r = 0; r < 4; ++r) {
      float inv = 1.f / lrow[mt][r];
      int n = qt * 128 + wv * 32 + mt * 16 + qd * 4 + r;
      size_t rowoff = ((size_t)b * SEQ + n) * (HEADS * DIM) + h * DIM;
      for (int nt = 0; nt < 8; ++nt)
        Z[rowoff + nt * 16 + l16] = bf16bits(o[mt][nt][r] * inv);
    }
}

// ---------------------------------------------------------------------------
// Kernel 3: out = Z(8192x1024) @ wot^T + b_out, fp32 out
// tile 64M x 128N, K chunks of 128, register-prefetched staging
// ---------------------------------------------------------------------------
__global__ __launch_bounds__(256, 2)
void out_kernel(const unsigned short* __restrict__ ws, const float* __restrict__ bias,
                float* __restrict__ out) {
  const unsigned short* Z   = ws + (size_t)3 * QSZ;
  const unsigned short* wot = ws;          // prep2 put bf16 w_out^T here
  const int m0 = blockIdx.x * 64;
  __shared__ __align__(16) unsigned short As[64 * 136];   // [m][k]
  __shared__ __align__(16) unsigned short Bt[128 * 136];  // [n][k]

  const int t = threadIdx.x, lane = t & 63, wv = t >> 6;
  const int l16 = lane & 15, qd = lane >> 4;

  // staging indices: A 1024 chunks (4/thread), B 2048 chunks (8/thread)
  int ar[4], ac[4], br[8], bc[8];
  for (int i = 0; i < 4; ++i) { int cid = i * 256 + t; ar[i] = cid >> 4; ac[i] = cid & 15; }
  for (int i = 0; i < 8; ++i) { int cid = i * 256 + t; br[i] = cid >> 4; bc[i] = cid & 15; }

  bf16x8 areg[4], breg[8];
  auto fetch = [&](int k0) {
    for (int i = 0; i < 4; ++i)
      areg[i] = *(const bf16x8*)(Z + (size_t)(m0 + ar[i]) * 1024 + k0 + ac[i] * 8);
    for (int i = 0; i < 8; ++i)
      breg[i] = *(const bf16x8*)(wot + (size_t)br[i] * 1024 + k0 + bc[i] * 8);
  };
  fetch(0);

  floatx4 acc[8] = {};
  for (int k0 = 0; k0 < 1024; k0 += 128) {
    __syncthreads();
    for (int i = 0; i < 4; ++i) *(bf16x8*)&As[ar[i] * 136 + ac[i] * 8] = areg[i];
    for (int i = 0; i < 8; ++i) *(bf16x8*)&Bt[br[i] * 136 + bc[i] * 8] = breg[i];
    __syncthreads();
    if (k0 < 896) fetch(k0 + 128);

    for (int ks = 0; ks < 4; ++ks) {
      bf16x8 af = *(const bf16x8*)&As[(wv * 16 + l16) * 136 + ks * 32 + qd * 8];
      for (int nt = 0; nt < 8; ++nt) {
        bf16x8 bfv = *(const bf16x8*)&Bt[(nt * 16 + l16) * 136 + ks * 32 + qd * 8];
        acc[nt] = __builtin_amdgcn_mfma_f32_16x16x32_bf16(af, bfv, acc[nt], 0, 0, 0);
      }
    }
  }

  for (int nt = 0; nt < 8; ++nt)
    for (int r = 0; r < 4; ++r) {
      int row = m0 + wv * 16 + qd * 4 + r;
      int col = nt * 16 + l16;
      out[(size_t)row * DIM + col] = acc[nt][r] + bias[col];
    }
}

extern "C" void kernel_launch(void* const* d_in, const int* in_sizes, int n_in,
                              void* d_out, int out_size, void* d_ws, size_t ws_size,
                              hipStream_t stream) {
  (void)in_sizes; (void)n_in; (void)out_size; (void)ws_size;
  const float* x     = (const float*)d_in[0];
  const float* w_qkv = (const float*)d_in[1];
  const float* w_out = (const float*)d_in[2];
  const float* b_out = (const float*)d_in[3];
  float* out = (float*)d_out;
  unsigned short* ws = (unsigned short*)d_ws;   // uses 4*QSZ*2 = 64 MiB

  prep1_kernel<<<dim3(560), dim3(256), 0, stream>>>(x, w_qkv, ws);
  qkv_kernel<<<dim3(64 * 48), dim3(256), 0, stream>>>(ws);
  attn_kernel<<<dim3(64 * 8), dim3(256), 0, stream>>>(ws);
  prep2_kernel<<<dim3(8), dim3(256), 0, stream>>>(w_out, ws);
  out_kernel<<<dim3(128), dim3(256), 0, stream>>>(ws, b_out, out);
}